// Round 2
// baseline (4085.623 us; speedup 1.0000x reference)
//
#include <hip/hip_runtime.h>
#include <hip/hip_bf16.h>

// GNN layer, bf16-MFMA restructuring:
//   AB = nf @ [We1_s | We1_d]      [N,512] bf16  (A|B interleaved per row)
//   C  = ef @ We1_e                [chunk,256] bf16 (chunked)
//   H[d] += lrelu(A[s]+B[d]+C[e]); H[s] += lrelu(A[d]+B[s]+C[e])  (fp32 atomics)
//   red = Hb @ We2 ; hid = lrelu([nf|red]@Wn1) ; out = hid @ Wn2
// All GEMMs: 128x128 tile, 4 waves, mfma_f32_16x16x32_bf16, fp32 accum.
// Weights pre-transposed to [N,K] bf16 so B-fragments are contiguous k-runs.

using f32x4  = __attribute__((ext_vector_type(4))) float;
using bf16x8 = __attribute__((ext_vector_type(8))) short;

#define LROW 72   // LDS row pitch in bf16 units (144 B): 8-cycle bank floor, no extra conflicts

__device__ __forceinline__ float lrelu(float x) { return x >= 0.f ? x : 0.01f * x; }

__device__ __forceinline__ ushort f2bf(float f) {
    union { float f; unsigned u; } v; v.f = f;
    unsigned u = v.u;
    return (ushort)((u + 0x7fffu + ((u >> 16) & 1u)) >> 16);   // RNE
}
__device__ __forceinline__ float bf2f(ushort u) {
    union { unsigned u; float f; } v; v.u = ((unsigned)u) << 16; return v.f;
}

// out[M,Nw] = cat(X1[M,K1], X2[M,K2]) @ Wt^T   (Wt is [Nw,K] bf16, n-major)
// M (grid.x*128) must be fully padded; stores guarded by Mstore.
// flags: 1 = lrelu, 2 = bf16 output (else fp32)
__global__ __launch_bounds__(256) void gemm_bf16(
    const ushort* __restrict__ X1, int K1,
    const ushort* __restrict__ X2, int K2,
    const ushort* __restrict__ Wt,
    void* __restrict__ out, int Nw, int Mstore, int flags)
{
    __shared__ ushort Xs[128 * LROW];
    __shared__ ushort Ws[128 * LROW];

    const int K    = K1 + K2;
    const int tid  = threadIdx.x;
    const int lane = tid & 63;
    const int wv   = tid >> 6;
    const int wm   = wv >> 1, wn = wv & 1;
    const int row0 = blockIdx.x * 128;
    const int col0 = blockIdx.y * 128;

    f32x4 acc[4][4] = {};

    for (int k0 = 0; k0 < K; k0 += 64) {
        const ushort* Xsrc; int kloc, ksz;
        if (k0 < K1) { Xsrc = X1; kloc = k0;      ksz = K1; }
        else         { Xsrc = X2; kloc = k0 - K1; ksz = K2; }

        const int r_  = tid >> 3;          // 0..31
        const int kk  = (tid & 7) * 8;     // bf16 offset 0..56
        uint4 xv[4], wvv[4];
        #pragma unroll
        for (int p = 0; p < 4; ++p) {
            int r = p * 32 + r_;
            xv[p]  = *reinterpret_cast<const uint4*>(Xsrc + (size_t)(row0 + r) * ksz + kloc + kk);
            wvv[p] = *reinterpret_cast<const uint4*>(Wt   + (size_t)(col0 + r) * K   + k0   + kk);
        }
        __syncthreads();   // prior iteration's LDS reads complete
        #pragma unroll
        for (int p = 0; p < 4; ++p) {
            int r = p * 32 + r_;
            *reinterpret_cast<uint4*>(&Xs[r * LROW + kk]) = xv[p];
            *reinterpret_cast<uint4*>(&Ws[r * LROW + kk]) = wvv[p];
        }
        __syncthreads();

        #pragma unroll
        for (int ks = 0; ks < 2; ++ks) {
            bf16x8 af[4], bfr[4];
            #pragma unroll
            for (int i = 0; i < 4; ++i) {
                int mrow = wm * 64 + i * 16 + (lane & 15);
                af[i]  = *reinterpret_cast<const bf16x8*>(&Xs[mrow * LROW + ks * 32 + (lane >> 4) * 8]);
                int ncol = wn * 64 + i * 16 + (lane & 15);
                bfr[i] = *reinterpret_cast<const bf16x8*>(&Ws[ncol * LROW + ks * 32 + (lane >> 4) * 8]);
            }
            #pragma unroll
            for (int i = 0; i < 4; ++i)
                #pragma unroll
                for (int j = 0; j < 4; ++j)
                    acc[i][j] = __builtin_amdgcn_mfma_f32_16x16x32_bf16(af[i], bfr[j], acc[i][j], 0, 0, 0);
        }
    }

    // C/D layout: col = lane&15, row = (lane>>4)*4 + reg
    #pragma unroll
    for (int i = 0; i < 4; ++i) {
        int gr0 = row0 + wm * 64 + i * 16 + ((lane >> 4) << 2);
        #pragma unroll
        for (int j = 0; j < 4; ++j) {
            int gc = col0 + wn * 64 + j * 16 + (lane & 15);
            #pragma unroll
            for (int r = 0; r < 4; ++r) {
                int gr = gr0 + r;
                if (gr >= Mstore) continue;
                float v = acc[i][j][r];
                if (flags & 1) v = lrelu(v);
                if (flags & 2) ((ushort*)out)[(size_t)gr * Nw + gc] = f2bf(v);
                else           ((float*) out)[(size_t)gr * Nw + gc] = v;
            }
        }
    }
}

// one wave per edge; lane covers 4 features
__global__ __launch_bounds__(256) void edge_pass(
    const ushort* __restrict__ AB,   // [Np,512] bf16: row = [A(256) | B(256)]
    const ushort* __restrict__ C,    // [chunk,256] bf16
    const int* __restrict__ src, const int* __restrict__ dst,
    float* __restrict__ H, int e0, int e1)
{
    int e = e0 + blockIdx.x * 4 + (threadIdx.x >> 6);
    if (e >= e1) return;
    int lane = threadIdx.x & 63;
    int s = src[e], d = dst[e];
    const ushort4 as = *(const ushort4*)(AB + (size_t)s * 512 +       lane * 4);
    const ushort4 bs = *(const ushort4*)(AB + (size_t)s * 512 + 256 + lane * 4);
    const ushort4 ad = *(const ushort4*)(AB + (size_t)d * 512 +       lane * 4);
    const ushort4 bd = *(const ushort4*)(AB + (size_t)d * 512 + 256 + lane * 4);
    const ushort4 cv = *(const ushort4*)(C + (size_t)(e - e0) * 256 + lane * 4);
    float c0 = bf2f(cv.x), c1 = bf2f(cv.y), c2 = bf2f(cv.z), c3 = bf2f(cv.w);
    float* Hd = H + (size_t)d * 256 + lane * 4;
    float* Hs = H + (size_t)s * 256 + lane * 4;
    atomicAdd(Hd + 0, lrelu(bf2f(as.x) + bf2f(bd.x) + c0));
    atomicAdd(Hd + 1, lrelu(bf2f(as.y) + bf2f(bd.y) + c1));
    atomicAdd(Hd + 2, lrelu(bf2f(as.z) + bf2f(bd.z) + c2));
    atomicAdd(Hd + 3, lrelu(bf2f(as.w) + bf2f(bd.w) + c3));
    atomicAdd(Hs + 0, lrelu(bf2f(ad.x) + bf2f(bs.x) + c0));
    atomicAdd(Hs + 1, lrelu(bf2f(ad.y) + bf2f(bs.y) + c1));
    atomicAdd(Hs + 2, lrelu(bf2f(ad.z) + bf2f(bs.z) + c2));
    atomicAdd(Hs + 3, lrelu(bf2f(ad.w) + bf2f(bs.w) + c3));
}

// float -> bf16 with zero padding; n_real, n_pad multiples of 4; grid covers n_pad/4 threads
__global__ __launch_bounds__(256) void cvt_pad(
    const float* __restrict__ x, ushort* __restrict__ y, size_t n_real, size_t n_pad)
{
    size_t i = ((size_t)blockIdx.x * 256 + threadIdx.x) * 4;
    if (i >= n_pad) return;
    ushort4 o;
    if (i < n_real) {
        float4 v = *(const float4*)(x + i);
        o.x = f2bf(v.x); o.y = f2bf(v.y); o.z = f2bf(v.z); o.w = f2bf(v.w);
    } else { o.x = 0; o.y = 0; o.z = 0; o.w = 0; }
    *(ushort4*)(y + i) = o;
}

// transpose + convert all weights to bf16 [N,K] layouts
__global__ __launch_bounds__(256) void wcvt(
    const float* __restrict__ We1, const float* __restrict__ We2,
    const float* __restrict__ Wn1, const float* __restrict__ Wn2,
    ushort* __restrict__ Wabt, ushort* __restrict__ Wet, ushort* __restrict__ We2t,
    ushort* __restrict__ Wn1t, ushort* __restrict__ Wn2t)
{
    int idx = blockIdx.x * 256 + threadIdx.x;
    switch (blockIdx.y) {
    case 0: if (idx < 256*128) { int n = idx >> 7, k = idx & 127; Wabt[idx]            = f2bf(We1[k * 256 + n]); } break;
    case 1: if (idx < 256*128) { int n = idx >> 7, k = idx & 127; Wabt[32768 + idx]    = f2bf(We1[(128 + k) * 256 + n]); } break;
    case 2: if (idx < 256*64)  { int n = idx >> 6, k = idx & 63;  Wet[idx]             = f2bf(We1[(256 + k) * 256 + n]); } break;
    case 3: if (idx < 128*256) { int n = idx >> 8, k = idx & 255; We2t[idx]            = f2bf(We2[k * 128 + n]); } break;
    case 4: if (idx < 256*256) { int n = idx >> 8, k = idx & 255; Wn1t[idx]            = f2bf(Wn1[k * 256 + n]); } break;
    case 5: if (idx < 128*256) { int n = idx >> 8, k = idx & 255; Wn2t[idx]            = f2bf(Wn2[k * 128 + n]); } break;
    }
}

extern "C" void kernel_launch(void* const* d_in, const int* in_sizes, int n_in,
                              void* d_out, int out_size, void* d_ws, size_t ws_size,
                              hipStream_t stream) {
    const float* nf  = (const float*)d_in[0];
    const float* ef  = (const float*)d_in[1];
    const int*   src = (const int*)d_in[2];
    const int*   dst = (const int*)d_in[3];
    const float* We1 = (const float*)d_in[4];
    const float* We2 = (const float*)d_in[5];
    const float* Wn1 = (const float*)d_in[6];
    const float* Wn2 = (const float*)d_in[7];
    float* out = (float*)d_out;

    const int  N  = in_sizes[0] / 128;            // 100000
    const int  E  = in_sizes[2];                  // 500000
    const int  Np = (N + 127) & ~127;             // 100096
    const long Ep = ((long)E + 127) & ~127L;      // 500096

    char* p = (char*)d_ws;
    auto alloc = [&](size_t bytes) { char* r = p; p += (bytes + 255) & ~(size_t)255; return r; };
    ushort* AB   = (ushort*)alloc((size_t)Np * 512 * 2);
    float*  H    = (float*) alloc((size_t)Np * 256 * 4);
    ushort* Hb   = (ushort*)alloc((size_t)Np * 256 * 2);
    ushort* nfb  = (ushort*)alloc((size_t)Np * 128 * 2);
    ushort* efb  = (ushort*)alloc((size_t)Ep * 64 * 2);
    ushort* Wabt = (ushort*)alloc(65536 * 2);
    ushort* Wet  = (ushort*)alloc(16384 * 2);
    ushort* We2t = (ushort*)alloc(32768 * 2);
    ushort* Wn1t = (ushort*)alloc(65536 * 2);
    ushort* Wn2t = (ushort*)alloc(32768 * 2);
    size_t rem = ws_size > (size_t)(p - (char*)d_ws) ? ws_size - (size_t)(p - (char*)d_ws) : 0;
    long maxrows = (long)(rem / 512);             // 256 bf16 per C row
    long chunk = 131072;
    if (maxrows >= Ep) chunk = Ep;
    else if (maxrows < chunk) chunk = (maxrows / 128) * 128;
    ushort* Cb  = (ushort*)p;
    ushort* red = AB;                              // alias: AB dead after edge pass
    ushort* hid = AB + (size_t)Np * 128;

    dim3 blk(256);

    wcvt<<<dim3(256, 6), blk, 0, stream>>>(We1, We2, Wn1, Wn2, Wabt, Wet, We2t, Wn1t, Wn2t);
    cvt_pad<<<dim3((unsigned)((size_t)Np * 128 / 1024)), blk, 0, stream>>>(nf, nfb, (size_t)N * 128, (size_t)Np * 128);
    cvt_pad<<<dim3((unsigned)((size_t)Ep * 64 / 1024)), blk, 0, stream>>>(ef, efb, (size_t)E * 64, (size_t)Ep * 64);

    // AB = nf @ [We1_s | We1_d]
    gemm_bf16<<<dim3(Np / 128, 4), blk, 0, stream>>>(nfb, 128, nullptr, 0, Wabt, AB, 512, Np, 2);

    hipMemsetAsync(H, 0, (size_t)Np * 256 * 4, stream);

    for (long e0 = 0; e0 < E; e0 += chunk) {
        long crows = (Ep - e0 < chunk) ? Ep - e0 : chunk;   // padded rows this chunk
        gemm_bf16<<<dim3((unsigned)(crows / 128), 2), blk, 0, stream>>>(
            efb + (size_t)e0 * 64, 64, nullptr, 0, Wet, Cb, 256, (int)crows, 2);
        long ereal = (E - e0 < chunk) ? E - e0 : chunk;
        edge_pass<<<dim3((unsigned)((ereal + 3) / 4)), blk, 0, stream>>>(
            AB, Cb, src, dst, H, (int)e0, (int)(e0 + ereal));
    }

    cvt_pad<<<dim3((unsigned)((size_t)Np * 256 / 1024)), blk, 0, stream>>>(H, Hb, (size_t)Np * 256, (size_t)Np * 256);

    // red = Hb @ We2
    gemm_bf16<<<dim3(Np / 128, 1), blk, 0, stream>>>(Hb, 256, nullptr, 0, We2t, red, 128, Np, 2);
    // hid = lrelu([nf|red] @ Wn1)
    gemm_bf16<<<dim3(Np / 128, 2), blk, 0, stream>>>(nfb, 128, red, 128, Wn1t, hid, 256, Np, 2 | 1);
    // out = hid @ Wn2  (fp32, guarded stores)
    gemm_bf16<<<dim3(Np / 128, 1), blk, 0, stream>>>(hid, 256, nullptr, 0, Wn2t, (void*)out, 128, N, 0);
}

// Round 3
// 1564.831 us; speedup vs baseline: 2.6109x; 2.6109x over previous
//
#include <hip/hip_runtime.h>
#include <hip/hip_bf16.h>

// GNN layer, bf16-MFMA restructuring:
//   AB = nf @ [We1_s | We1_d]      [N,512] bf16  (A|B interleaved per row)
//   C  = ef @ We1_e                [chunk,256] bf16 (chunked)
//   H[d] += lrelu(A[s]+B[d]+C[e]); H[s] += lrelu(A[d]+B[s]+C[e])  (fp32 atomics)
//   red = Hb @ We2 ; hid = lrelu([nf|red]@Wn1) ; out = hid @ Wn2
// All GEMMs: 128x128 tile, 4 waves, mfma_f32_16x16x32_bf16, fp32 accum.
// edge_pass: one block per edge, thread j = feature j -> every wave-level
// load/atomic instruction touches 64 CONSECUTIVE dwords (4 cachelines).
// (Round-2 lesson: per-lane float4 atomics stride lanes 16B apart -> 16
// lines/instr -> 4x L2 transactions, 4x slower.)

using f32x4  = __attribute__((ext_vector_type(4))) float;
using bf16x8 = __attribute__((ext_vector_type(8))) short;

#define LROW 72   // LDS row pitch in bf16 units (144 B)

__device__ __forceinline__ float lrelu(float x) { return x >= 0.f ? x : 0.01f * x; }

__device__ __forceinline__ ushort f2bf(float f) {
    union { float f; unsigned u; } v; v.f = f;
    unsigned u = v.u;
    return (ushort)((u + 0x7fffu + ((u >> 16) & 1u)) >> 16);   // RNE
}
__device__ __forceinline__ float bf2f(ushort u) {
    union { unsigned u; float f; } v; v.u = ((unsigned)u) << 16; return v.f;
}

// out[M,Nw] = cat(X1[M,K1], X2[M,K2]) @ Wt^T   (Wt is [Nw,K] bf16, n-major)
// M (grid.x*128) must be fully padded; stores guarded by Mstore.
// flags: 1 = lrelu, 2 = bf16 output (else fp32)
__global__ __launch_bounds__(256) void gemm_bf16(
    const ushort* __restrict__ X1, int K1,
    const ushort* __restrict__ X2, int K2,
    const ushort* __restrict__ Wt,
    void* __restrict__ out, int Nw, int Mstore, int flags)
{
    __shared__ ushort Xs[128 * LROW];
    __shared__ ushort Ws[128 * LROW];

    const int K    = K1 + K2;
    const int tid  = threadIdx.x;
    const int lane = tid & 63;
    const int wv   = tid >> 6;
    const int wm   = wv >> 1, wn = wv & 1;
    const int row0 = blockIdx.x * 128;
    const int col0 = blockIdx.y * 128;

    f32x4 acc[4][4] = {};

    for (int k0 = 0; k0 < K; k0 += 64) {
        const ushort* Xsrc; int kloc, ksz;
        if (k0 < K1) { Xsrc = X1; kloc = k0;      ksz = K1; }
        else         { Xsrc = X2; kloc = k0 - K1; ksz = K2; }

        const int r_  = tid >> 3;          // 0..31
        const int kk  = (tid & 7) * 8;     // bf16 offset 0..56
        uint4 xv[4], wvv[4];
        #pragma unroll
        for (int p = 0; p < 4; ++p) {
            int r = p * 32 + r_;
            xv[p]  = *reinterpret_cast<const uint4*>(Xsrc + (size_t)(row0 + r) * ksz + kloc + kk);
            wvv[p] = *reinterpret_cast<const uint4*>(Wt   + (size_t)(col0 + r) * K   + k0   + kk);
        }
        __syncthreads();   // prior iteration's LDS reads complete
        #pragma unroll
        for (int p = 0; p < 4; ++p) {
            int r = p * 32 + r_;
            *reinterpret_cast<uint4*>(&Xs[r * LROW + kk]) = xv[p];
            *reinterpret_cast<uint4*>(&Ws[r * LROW + kk]) = wvv[p];
        }
        __syncthreads();

        #pragma unroll
        for (int ks = 0; ks < 2; ++ks) {
            bf16x8 af[4], bfr[4];
            #pragma unroll
            for (int i = 0; i < 4; ++i) {
                int mrow = wm * 64 + i * 16 + (lane & 15);
                af[i]  = *reinterpret_cast<const bf16x8*>(&Xs[mrow * LROW + ks * 32 + (lane >> 4) * 8]);
                int ncol = wn * 64 + i * 16 + (lane & 15);
                bfr[i] = *reinterpret_cast<const bf16x8*>(&Ws[ncol * LROW + ks * 32 + (lane >> 4) * 8]);
            }
            #pragma unroll
            for (int i = 0; i < 4; ++i)
                #pragma unroll
                for (int j = 0; j < 4; ++j)
                    acc[i][j] = __builtin_amdgcn_mfma_f32_16x16x32_bf16(af[i], bfr[j], acc[i][j], 0, 0, 0);
        }
    }

    // C/D layout: col = lane&15, row = (lane>>4)*4 + reg
    #pragma unroll
    for (int i = 0; i < 4; ++i) {
        int gr0 = row0 + wm * 64 + i * 16 + ((lane >> 4) << 2);
        #pragma unroll
        for (int j = 0; j < 4; ++j) {
            int gc = col0 + wn * 64 + j * 16 + (lane & 15);
            #pragma unroll
            for (int r = 0; r < 4; ++r) {
                int gr = gr0 + r;
                if (gr >= Mstore) continue;
                float v = acc[i][j][r];
                if (flags & 1) v = lrelu(v);
                if (flags & 2) ((ushort*)out)[(size_t)gr * Nw + gc] = f2bf(v);
                else           ((float*) out)[(size_t)gr * Nw + gc] = v;
            }
        }
    }
}

// one block (256 thr) per edge; thread j = feature j.
// All wave-level loads are 128B contiguous; atomics are 64 consecutive
// dwords per instruction (4 cachelines) -> maximal L2 merge.
__global__ __launch_bounds__(256) void edge_pass(
    const ushort* __restrict__ AB,   // [Np,512] bf16: row = [A(256) | B(256)]
    const ushort* __restrict__ C,    // [chunk,256] bf16
    const int* __restrict__ src, const int* __restrict__ dst,
    float* __restrict__ H, int e0, int e1)
{
    int e = e0 + blockIdx.x;
    if (e >= e1) return;
    int j = threadIdx.x;
    int s = src[e], d = dst[e];
    float c  = bf2f(C[(size_t)(e - e0) * 256 + j]);
    float as = bf2f(AB[(size_t)s * 512 + j]);
    float bs = bf2f(AB[(size_t)s * 512 + 256 + j]);
    float ad = bf2f(AB[(size_t)d * 512 + j]);
    float bd = bf2f(AB[(size_t)d * 512 + 256 + j]);
    atomicAdd(&H[(size_t)d * 256 + j], lrelu(as + bd + c));
    atomicAdd(&H[(size_t)s * 256 + j], lrelu(ad + bs + c));
}

// float -> bf16 with zero padding; n_real, n_pad multiples of 4
__global__ __launch_bounds__(256) void cvt_pad(
    const float* __restrict__ x, ushort* __restrict__ y, size_t n_real, size_t n_pad)
{
    size_t i = ((size_t)blockIdx.x * 256 + threadIdx.x) * 4;
    if (i >= n_pad) return;
    ushort4 o;
    if (i < n_real) {
        float4 v = *(const float4*)(x + i);
        o.x = f2bf(v.x); o.y = f2bf(v.y); o.z = f2bf(v.z); o.w = f2bf(v.w);
    } else { o.x = 0; o.y = 0; o.z = 0; o.w = 0; }
    *(ushort4*)(y + i) = o;
}

// transpose + convert all weights to bf16 [N,K] layouts
__global__ __launch_bounds__(256) void wcvt(
    const float* __restrict__ We1, const float* __restrict__ We2,
    const float* __restrict__ Wn1, const float* __restrict__ Wn2,
    ushort* __restrict__ Wabt, ushort* __restrict__ Wet, ushort* __restrict__ We2t,
    ushort* __restrict__ Wn1t, ushort* __restrict__ Wn2t)
{
    int idx = blockIdx.x * 256 + threadIdx.x;
    switch (blockIdx.y) {
    case 0: if (idx < 256*128) { int n = idx >> 7, k = idx & 127; Wabt[idx]            = f2bf(We1[k * 256 + n]); } break;
    case 1: if (idx < 256*128) { int n = idx >> 7, k = idx & 127; Wabt[32768 + idx]    = f2bf(We1[(128 + k) * 256 + n]); } break;
    case 2: if (idx < 256*64)  { int n = idx >> 6, k = idx & 63;  Wet[idx]             = f2bf(We1[(256 + k) * 256 + n]); } break;
    case 3: if (idx < 128*256) { int n = idx >> 8, k = idx & 255; We2t[idx]            = f2bf(We2[k * 128 + n]); } break;
    case 4: if (idx < 256*256) { int n = idx >> 8, k = idx & 255; Wn1t[idx]            = f2bf(Wn1[k * 256 + n]); } break;
    case 5: if (idx < 128*256) { int n = idx >> 8, k = idx & 255; Wn2t[idx]            = f2bf(Wn2[k * 128 + n]); } break;
    }
}

extern "C" void kernel_launch(void* const* d_in, const int* in_sizes, int n_in,
                              void* d_out, int out_size, void* d_ws, size_t ws_size,
                              hipStream_t stream) {
    const float* nf  = (const float*)d_in[0];
    const float* ef  = (const float*)d_in[1];
    const int*   src = (const int*)d_in[2];
    const int*   dst = (const int*)d_in[3];
    const float* We1 = (const float*)d_in[4];
    const float* We2 = (const float*)d_in[5];
    const float* Wn1 = (const float*)d_in[6];
    const float* Wn2 = (const float*)d_in[7];
    float* out = (float*)d_out;

    const int  N  = in_sizes[0] / 128;            // 100000
    const int  E  = in_sizes[2];                  // 500000
    const int  Np = (N + 127) & ~127;             // 100096
    const long Ep = ((long)E + 127) & ~127L;      // 500096

    char* p = (char*)d_ws;
    auto alloc = [&](size_t bytes) { char* r = p; p += (bytes + 255) & ~(size_t)255; return r; };
    ushort* AB   = (ushort*)alloc((size_t)Np * 512 * 2);
    float*  H    = (float*) alloc((size_t)Np * 256 * 4);
    ushort* Hb   = (ushort*)alloc((size_t)Np * 256 * 2);
    ushort* nfb  = (ushort*)alloc((size_t)Np * 128 * 2);
    ushort* efb  = (ushort*)alloc((size_t)Ep * 64 * 2);
    ushort* Wabt = (ushort*)alloc(65536 * 2);
    ushort* Wet  = (ushort*)alloc(16384 * 2);
    ushort* We2t = (ushort*)alloc(32768 * 2);
    ushort* Wn1t = (ushort*)alloc(65536 * 2);
    ushort* Wn2t = (ushort*)alloc(32768 * 2);
    size_t rem = ws_size > (size_t)(p - (char*)d_ws) ? ws_size - (size_t)(p - (char*)d_ws) : 0;
    long maxrows = (long)(rem / 512);             // 256 bf16 per C row
    long chunk = 131072;
    if (maxrows >= Ep) chunk = Ep;
    else if (maxrows < chunk) chunk = (maxrows / 128) * 128;
    ushort* Cb  = (ushort*)p;
    ushort* red = AB;                              // alias: AB dead after edge pass
    ushort* hid = AB + (size_t)Np * 128;

    dim3 blk(256);

    wcvt<<<dim3(256, 6), blk, 0, stream>>>(We1, We2, Wn1, Wn2, Wabt, Wet, We2t, Wn1t, Wn2t);
    cvt_pad<<<dim3((unsigned)((size_t)Np * 128 / 1024)), blk, 0, stream>>>(nf, nfb, (size_t)N * 128, (size_t)Np * 128);
    cvt_pad<<<dim3((unsigned)((size_t)Ep * 64 / 1024)), blk, 0, stream>>>(ef, efb, (size_t)E * 64, (size_t)Ep * 64);

    // AB = nf @ [We1_s | We1_d]
    gemm_bf16<<<dim3(Np / 128, 4), blk, 0, stream>>>(nfb, 128, nullptr, 0, Wabt, AB, 512, Np, 2);

    hipMemsetAsync(H, 0, (size_t)Np * 256 * 4, stream);

    for (long e0 = 0; e0 < E; e0 += chunk) {
        long crows = (Ep - e0 < chunk) ? Ep - e0 : chunk;   // padded rows this chunk
        gemm_bf16<<<dim3((unsigned)(crows / 128), 2), blk, 0, stream>>>(
            efb + (size_t)e0 * 64, 64, nullptr, 0, Wet, Cb, 256, (int)crows, 2);
        long ereal = (E - e0 < chunk) ? E - e0 : chunk;
        edge_pass<<<dim3((unsigned)ereal), blk, 0, stream>>>(
            AB, Cb, src, dst, H, (int)e0, (int)(e0 + ereal));
    }

    cvt_pad<<<dim3((unsigned)((size_t)Np * 256 / 1024)), blk, 0, stream>>>(H, Hb, (size_t)Np * 256, (size_t)Np * 256);

    // red = Hb @ We2
    gemm_bf16<<<dim3(Np / 128, 1), blk, 0, stream>>>(Hb, 256, nullptr, 0, We2t, red, 128, Np, 2);
    // hid = lrelu([nf|red] @ Wn1)
    gemm_bf16<<<dim3(Np / 128, 2), blk, 0, stream>>>(nfb, 128, red, 128, Wn1t, hid, 256, Np, 2 | 1);
    // out = hid @ Wn2  (fp32, guarded stores)
    gemm_bf16<<<dim3(Np / 128, 1), blk, 0, stream>>>(hid, 256, nullptr, 0, Wn2t, (void*)out, 128, N, 0);
}

// Round 4
// 1127.011 us; speedup vs baseline: 3.6252x; 1.3885x over previous
//
#include <hip/hip_runtime.h>
#include <hip/hip_bf16.h>
#include <string.h>

// GNN layer, bf16-MFMA restructuring:
//   AB = nf @ [We1_s | We1_d]      [N,512] bf16  (A|B halves per row)
//   C  = ef @ We1_e                [chunk,256] bf16 (chunked)
//   H[d] += lrelu(A[s]+B[d]+C[e]); H[s] += lrelu(A[d]+B[s]+C[e])
//        H is bf16, accumulated with native global_atomic_pk_add_bf16
//        (halves atomic payload + table vs fp32; H feeds next GEMM directly)
//   red = H @ We2 ; hid = lrelu([nf|red]@Wn1) ; out = hid @ Wn2
// All GEMMs: 128x128 tile, 4 waves, mfma_f32_16x16x32_bf16, fp32 accum.
// edge_pass: thread j = feature pair (2j,2j+1) -> every wave-level
// load/atomic instruction touches 256B CONSECUTIVE bytes (round-2 lesson:
// strided per-lane atomics are 4x slower).

using f32x4  = __attribute__((ext_vector_type(4))) float;
using bf16x8 = __attribute__((ext_vector_type(8))) short;

#define LROW 72   // LDS row pitch in bf16 units (144 B)

__device__ __forceinline__ float lrelu(float x) { return x >= 0.f ? x : 0.01f * x; }

__device__ __forceinline__ ushort f2bf(float f) {
    union { float f; unsigned u; } v; v.f = f;
    unsigned u = v.u;
    return (ushort)((u + 0x7fffu + ((u >> 16) & 1u)) >> 16);   // RNE
}
__device__ __forceinline__ float bf2f(ushort u) {
    union { unsigned u; float f; } v; v.u = ((unsigned)u) << 16; return v.f;
}

// native packed bf16 atomic add (gfx942+/gfx950); addr must be 4B-aligned
__device__ __forceinline__ void atomic_pk_add_bf16(void* addr, unsigned val) {
    asm volatile("global_atomic_pk_add_bf16 %0, %1, off" : : "v"(addr), "v"(val) : "memory");
}

// out[M,Nw] = cat(X1[M,K1], X2[M,K2]) @ Wt^T   (Wt is [Nw,K] bf16, n-major)
// M (grid.x*128) must be fully padded; stores guarded by Mstore.
// flags: 1 = lrelu, 2 = bf16 output (else fp32)
__global__ __launch_bounds__(256) void gemm_bf16(
    const ushort* __restrict__ X1, int K1,
    const ushort* __restrict__ X2, int K2,
    const ushort* __restrict__ Wt,
    void* __restrict__ out, int Nw, int Mstore, int flags)
{
    __shared__ ushort Xs[128 * LROW];
    __shared__ ushort Ws[128 * LROW];

    const int K    = K1 + K2;
    const int tid  = threadIdx.x;
    const int lane = tid & 63;
    const int wv   = tid >> 6;
    const int wm   = wv >> 1, wn = wv & 1;
    const int row0 = blockIdx.x * 128;
    const int col0 = blockIdx.y * 128;

    f32x4 acc[4][4] = {};

    for (int k0 = 0; k0 < K; k0 += 64) {
        const ushort* Xsrc; int kloc, ksz;
        if (k0 < K1) { Xsrc = X1; kloc = k0;      ksz = K1; }
        else         { Xsrc = X2; kloc = k0 - K1; ksz = K2; }

        const int r_  = tid >> 3;          // 0..31
        const int kk  = (tid & 7) * 8;     // bf16 offset 0..56
        uint4 xv[4], wvv[4];
        #pragma unroll
        for (int p = 0; p < 4; ++p) {
            int r = p * 32 + r_;
            xv[p]  = *reinterpret_cast<const uint4*>(Xsrc + (size_t)(row0 + r) * ksz + kloc + kk);
            wvv[p] = *reinterpret_cast<const uint4*>(Wt   + (size_t)(col0 + r) * K   + k0   + kk);
        }
        __syncthreads();   // prior iteration's LDS reads complete
        #pragma unroll
        for (int p = 0; p < 4; ++p) {
            int r = p * 32 + r_;
            *reinterpret_cast<uint4*>(&Xs[r * LROW + kk]) = xv[p];
            *reinterpret_cast<uint4*>(&Ws[r * LROW + kk]) = wvv[p];
        }
        __syncthreads();

        #pragma unroll
        for (int ks = 0; ks < 2; ++ks) {
            bf16x8 af[4], bfr[4];
            #pragma unroll
            for (int i = 0; i < 4; ++i) {
                int mrow = wm * 64 + i * 16 + (lane & 15);
                af[i]  = *reinterpret_cast<const bf16x8*>(&Xs[mrow * LROW + ks * 32 + (lane >> 4) * 8]);
                int ncol = wn * 64 + i * 16 + (lane & 15);
                bfr[i] = *reinterpret_cast<const bf16x8*>(&Ws[ncol * LROW + ks * 32 + (lane >> 4) * 8]);
            }
            #pragma unroll
            for (int i = 0; i < 4; ++i)
                #pragma unroll
                for (int j = 0; j < 4; ++j)
                    acc[i][j] = __builtin_amdgcn_mfma_f32_16x16x32_bf16(af[i], bfr[j], acc[i][j], 0, 0, 0);
        }
    }

    // C/D layout: col = lane&15, row = (lane>>4)*4 + reg
    #pragma unroll
    for (int i = 0; i < 4; ++i) {
        int gr0 = row0 + wm * 64 + i * 16 + ((lane >> 4) << 2);
        #pragma unroll
        for (int j = 0; j < 4; ++j) {
            int gc = col0 + wn * 64 + j * 16 + (lane & 15);
            #pragma unroll
            for (int r = 0; r < 4; ++r) {
                int gr = gr0 + r;
                if (gr >= Mstore) continue;
                float v = acc[i][j][r];
                if (flags & 1) v = lrelu(v);
                if (flags & 2) ((ushort*)out)[(size_t)gr * Nw + gc] = f2bf(v);
                else           ((float*) out)[(size_t)gr * Nw + gc] = v;
            }
        }
    }
}

// 2 edges per 256-thread block; thread j (0..127) = feature pair (2j, 2j+1).
// Per wave instruction: 64 lanes x 4B = 256B contiguous loads/atomics.
__global__ __launch_bounds__(256) void edge_pass(
    const ushort* __restrict__ AB,   // [Np,512] bf16: row = [A(256) | B(256)]
    const ushort* __restrict__ C,    // [chunk,256] bf16
    const int* __restrict__ src, const int* __restrict__ dst,
    ushort* __restrict__ H,          // [Np,256] bf16 accumulator
    int e0, int e1)
{
    int e = e0 + blockIdx.x * 2 + (threadIdx.x >> 7);
    if (e >= e1) return;
    int j = (threadIdx.x & 127) * 2;
    int s = src[e], d = dst[e];
    ushort2 cv = *(const ushort2*)(C + (size_t)(e - e0) * 256 + j);
    ushort2 as = *(const ushort2*)(AB + (size_t)s * 512 + j);
    ushort2 bs = *(const ushort2*)(AB + (size_t)s * 512 + 256 + j);
    ushort2 ad = *(const ushort2*)(AB + (size_t)d * 512 + j);
    ushort2 bd = *(const ushort2*)(AB + (size_t)d * 512 + 256 + j);
    float c0 = bf2f(cv.x), c1 = bf2f(cv.y);
    ushort2 mf, mb;
    mf.x = f2bf(lrelu(bf2f(as.x) + bf2f(bd.x) + c0));
    mf.y = f2bf(lrelu(bf2f(as.y) + bf2f(bd.y) + c1));
    mb.x = f2bf(lrelu(bf2f(ad.x) + bf2f(bs.x) + c0));
    mb.y = f2bf(lrelu(bf2f(ad.y) + bf2f(bs.y) + c1));
    unsigned uf, ub;
    memcpy(&uf, &mf, 4); memcpy(&ub, &mb, 4);
    atomic_pk_add_bf16(H + (size_t)d * 256 + j, uf);
    atomic_pk_add_bf16(H + (size_t)s * 256 + j, ub);
}

// float -> bf16 with zero padding; n_real, n_pad multiples of 4
__global__ __launch_bounds__(256) void cvt_pad(
    const float* __restrict__ x, ushort* __restrict__ y, size_t n_real, size_t n_pad)
{
    size_t i = ((size_t)blockIdx.x * 256 + threadIdx.x) * 4;
    if (i >= n_pad) return;
    ushort4 o;
    if (i < n_real) {
        float4 v = *(const float4*)(x + i);
        o.x = f2bf(v.x); o.y = f2bf(v.y); o.z = f2bf(v.z); o.w = f2bf(v.w);
    } else { o.x = 0; o.y = 0; o.z = 0; o.w = 0; }
    *(ushort4*)(y + i) = o;
}

// transpose + convert all weights to bf16 [N,K] layouts
__global__ __launch_bounds__(256) void wcvt(
    const float* __restrict__ We1, const float* __restrict__ We2,
    const float* __restrict__ Wn1, const float* __restrict__ Wn2,
    ushort* __restrict__ Wabt, ushort* __restrict__ Wet, ushort* __restrict__ We2t,
    ushort* __restrict__ Wn1t, ushort* __restrict__ Wn2t)
{
    int idx = blockIdx.x * 256 + threadIdx.x;
    switch (blockIdx.y) {
    case 0: if (idx < 256*128) { int n = idx >> 7, k = idx & 127; Wabt[idx]            = f2bf(We1[k * 256 + n]); } break;
    case 1: if (idx < 256*128) { int n = idx >> 7, k = idx & 127; Wabt[32768 + idx]    = f2bf(We1[(128 + k) * 256 + n]); } break;
    case 2: if (idx < 256*64)  { int n = idx >> 6, k = idx & 63;  Wet[idx]             = f2bf(We1[(256 + k) * 256 + n]); } break;
    case 3: if (idx < 128*256) { int n = idx >> 8, k = idx & 255; We2t[idx]            = f2bf(We2[k * 128 + n]); } break;
    case 4: if (idx < 256*256) { int n = idx >> 8, k = idx & 255; Wn1t[idx]            = f2bf(Wn1[k * 256 + n]); } break;
    case 5: if (idx < 128*256) { int n = idx >> 8, k = idx & 255; Wn2t[idx]            = f2bf(Wn2[k * 128 + n]); } break;
    }
}

extern "C" void kernel_launch(void* const* d_in, const int* in_sizes, int n_in,
                              void* d_out, int out_size, void* d_ws, size_t ws_size,
                              hipStream_t stream) {
    const float* nf  = (const float*)d_in[0];
    const float* ef  = (const float*)d_in[1];
    const int*   src = (const int*)d_in[2];
    const int*   dst = (const int*)d_in[3];
    const float* We1 = (const float*)d_in[4];
    const float* We2 = (const float*)d_in[5];
    const float* Wn1 = (const float*)d_in[6];
    const float* Wn2 = (const float*)d_in[7];
    float* out = (float*)d_out;

    const int  N  = in_sizes[0] / 128;            // 100000
    const int  E  = in_sizes[2];                  // 500000
    const int  Np = (N + 127) & ~127;             // 100096
    const long Ep = ((long)E + 127) & ~127L;      // 500096

    char* p = (char*)d_ws;
    auto alloc = [&](size_t bytes) { char* r = p; p += (bytes + 255) & ~(size_t)255; return r; };
    ushort* AB   = (ushort*)alloc((size_t)Np * 512 * 2);
    ushort* H    = (ushort*)alloc((size_t)Np * 256 * 2);   // bf16 accumulator
    ushort* nfb  = (ushort*)alloc((size_t)Np * 128 * 2);
    ushort* efb  = (ushort*)alloc((size_t)Ep * 64 * 2);
    ushort* Wabt = (ushort*)alloc(65536 * 2);
    ushort* Wet  = (ushort*)alloc(16384 * 2);
    ushort* We2t = (ushort*)alloc(32768 * 2);
    ushort* Wn1t = (ushort*)alloc(65536 * 2);
    ushort* Wn2t = (ushort*)alloc(32768 * 2);
    size_t rem = ws_size > (size_t)(p - (char*)d_ws) ? ws_size - (size_t)(p - (char*)d_ws) : 0;
    long maxrows = (long)(rem / 512);             // 256 bf16 per C row
    long chunk = (maxrows / 128) * 128;
    if (chunk > Ep) chunk = Ep;
    if (chunk < 128) chunk = 128;                 // last-resort; ws assumed adequate
    ushort* Cb  = (ushort*)p;
    ushort* red = AB;                              // alias: AB dead after edge pass
    ushort* hid = AB + (size_t)Np * 128;

    dim3 blk(256);

    wcvt<<<dim3(256, 6), blk, 0, stream>>>(We1, We2, Wn1, Wn2, Wabt, Wet, We2t, Wn1t, Wn2t);
    cvt_pad<<<dim3((unsigned)((size_t)Np * 128 / 1024)), blk, 0, stream>>>(nf, nfb, (size_t)N * 128, (size_t)Np * 128);
    cvt_pad<<<dim3((unsigned)((size_t)Ep * 64 / 1024)), blk, 0, stream>>>(ef, efb, (size_t)E * 64, (size_t)Ep * 64);

    // AB = nf @ [We1_s | We1_d]
    gemm_bf16<<<dim3(Np / 128, 4), blk, 0, stream>>>(nfb, 128, nullptr, 0, Wabt, AB, 512, Np, 2);

    hipMemsetAsync(H, 0, (size_t)Np * 256 * 2, stream);

    for (long e0 = 0; e0 < E; e0 += chunk) {
        long crows = (Ep - e0 < chunk) ? Ep - e0 : chunk;   // padded rows this chunk
        gemm_bf16<<<dim3((unsigned)(crows / 128), 2), blk, 0, stream>>>(
            efb + (size_t)e0 * 64, 64, nullptr, 0, Wet, Cb, 256, (int)crows, 2);
        long ereal = (E - e0 < chunk) ? E - e0 : chunk;
        edge_pass<<<dim3((unsigned)((ereal + 1) / 2)), blk, 0, stream>>>(
            AB, Cb, src, dst, H, (int)e0, (int)(e0 + ereal));
    }

    // red = H @ We2   (H already bf16 -> no convert pass)
    gemm_bf16<<<dim3(Np / 128, 1), blk, 0, stream>>>(H, 256, nullptr, 0, We2t, red, 128, Np, 2);
    // hid = lrelu([nf|red] @ Wn1)
    gemm_bf16<<<dim3(Np / 128, 2), blk, 0, stream>>>(nfb, 128, red, 128, Wn1t, hid, 256, Np, 2 | 1);
    // out = hid @ Wn2  (fp32, guarded stores)
    gemm_bf16<<<dim3(Np / 128, 1), blk, 0, stream>>>(hid, 256, nullptr, 0, Wn2t, (void*)out, 128, N, 0);
}